// Round 2
// baseline (953.164 us; speedup 1.0000x reference)
//
#include <hip/hip_runtime.h>

#define TPB   256
#define S_PIX 4096     // 64*64 pixels
#define NCH   256      // channels
#define NB    64       // batch
#define MAXC  1024     // provable max 8-connected comps in 64x64
#define KP    15       // K*P = 5*3

// ---------------- K0: normalize SFC prototypes ----------------
__global__ __launch_bounds__(TPB) void sfc_norm_kernel(
    const float* __restrict__ sfc, float* __restrict__ sn)
{
    int t = threadIdx.x;
    int kp = t >> 4;          // 16 lanes per prototype row
    int l  = t & 15;
    if (kp < KP) {
        const float* v = sfc + kp * NCH;
        float s = 0.f;
        for (int c = l; c < NCH; c += 16) { float x = v[c]; s += x * x; }
        #pragma unroll
        for (int m = 8; m >= 1; m >>= 1) s += __shfl_xor(s, m, 16);
        float inv = 1.f / fmaxf(sqrtf(s), 1e-12f);
        for (int c = l; c < NCH; c += 16) sn[kp * NCH + c] = v[c] * inv;
    }
}

// ---------------- K1: CCL (min-index prop + pointer jump) + compaction ----------------
__global__ __launch_bounds__(TPB) void ccl_compact_kernel(
    const int* __restrict__ mask, int* __restrict__ cid, int* __restrict__ ncomp)
{
    __shared__ int lab[S_PIX];
    __shared__ int rootid[S_PIX];
    __shared__ int changed;
    __shared__ int cnt;
    const int b = blockIdx.x;
    const int t = threadIdx.x;
    const int* mb = mask + b * S_PIX;

    for (int i = t; i < S_PIX; i += TPB)
        lab[i] = (mb[i] > 0) ? i : 0x7FFFFFFF;
    if (t == 0) { changed = 0; cnt = 0; }
    __syncthreads();

    for (;;) {
        int any = 0;
        for (int i = t; i < S_PIX; i += TPB) {
            int l = lab[i];
            if (l == 0x7FFFFFFF) continue;
            int x = i & 63;
            int mn = l;
            if (x > 0)  mn = min(mn, lab[i - 1]);
            if (x < 63) mn = min(mn, lab[i + 1]);
            if (i >= 64) {
                mn = min(mn, lab[i - 64]);
                if (x > 0)  mn = min(mn, lab[i - 65]);
                if (x < 63) mn = min(mn, lab[i - 63]);
            }
            if (i < S_PIX - 64) {
                mn = min(mn, lab[i + 64]);
                if (x > 0)  mn = min(mn, lab[i + 63]);
                if (x < 63) mn = min(mn, lab[i + 65]);
            }
            // pointer jumps (labels are fg pixel indices; monotone decreasing)
            mn = min(mn, lab[mn]);
            mn = min(mn, lab[mn]);
            if (mn < l) { lab[i] = mn; any = 1; }
        }
        if (any) changed = 1;
        __syncthreads();
        if (!changed) break;       // uniform: read after barrier, no writes since
        __syncthreads();
        if (t == 0) changed = 0;
        __syncthreads();
    }

    // compact: roots are fg pixels with lab[i]==i
    for (int i = t; i < S_PIX; i += TPB)
        if (lab[i] == i) rootid[i] = atomicAdd(&cnt, 1);
    __syncthreads();
    for (int i = t; i < S_PIX; i += TPB) {
        int l = lab[i];
        cid[b * S_PIX + i] = (l == 0x7FFFFFFF) ? -1 : rootid[l];
    }
    if (t == 0) ncomp[b] = cnt;
}

// ---------------- K2: per-comp channel-chunk sums -> partial dots + norm^2 ----------------
__global__ __launch_bounds__(TPB) void accum_kernel(
    const float* __restrict__ feat, const float* __restrict__ sn,
    const int* __restrict__ cid, const int* __restrict__ ncomp,
    float* __restrict__ pdots)
{
    __shared__ __align__(16) int scid[S_PIX];   // 16 KB
    __shared__ float acc[8 * MAXC];             // 32 KB, [ch_local][comp]
    __shared__ float snc[KP * 8];
    const int b  = blockIdx.y;
    const int c0 = blockIdx.x * 8;
    const int t  = threadIdx.x;

    { // stage cid as int4
        const int4* src = reinterpret_cast<const int4*>(cid + b * S_PIX);
        int4* dst = reinterpret_cast<int4*>(scid);
        for (int i = t; i < S_PIX / 4; i += TPB) dst[i] = src[i];
    }
    for (int i = t; i < 8 * MAXC; i += TPB) acc[i] = 0.f;
    if (t < KP * 8) {
        int kp = t >> 3, h = t & 7;
        snc[t] = sn[kp * NCH + c0 + h];
    }
    __syncthreads();

    const int wave = t >> 6, lane = t & 63;
    const float* fb = feat + (size_t)b * NCH * S_PIX;
    #pragma unroll
    for (int ccx = 0; ccx < 2; ++ccx) {
        const int chl = wave * 2 + ccx;
        const float* fr = fb + (size_t)(c0 + chl) * S_PIX;
        float* accc = acc + chl * MAXC;
        for (int base = 0; base < S_PIX; base += 256) {
            const int p = base + lane * 4;
            int4 q = *reinterpret_cast<const int4*>(&scid[p]);
            if ((q.x & q.y & q.z & q.w) == -1) continue;   // all background
            float4 v = *reinterpret_cast<const float4*>(&fr[p]);
            int cur = q.x; float rs = v.x;
            if (q.y == cur) rs += v.y; else { if (cur >= 0) atomicAdd(&accc[cur], rs); cur = q.y; rs = v.y; }
            if (q.z == cur) rs += v.z; else { if (cur >= 0) atomicAdd(&accc[cur], rs); cur = q.z; rs = v.z; }
            if (q.w == cur) rs += v.w; else { if (cur >= 0) atomicAdd(&accc[cur], rs); cur = q.w; rs = v.w; }
            if (cur >= 0) atomicAdd(&accc[cur], rs);
        }
    }
    __syncthreads();

    const int n = ncomp[b];
    for (int j = t; j < n; j += TPB) {
        float s[8]; float n2 = 0.f;
        #pragma unroll
        for (int h = 0; h < 8; ++h) { float x = acc[h * MAXC + j]; s[h] = x; n2 += x * x; }
        float* dst = pdots + (size_t)(b * MAXC + j) * 16;
        #pragma unroll
        for (int kp = 0; kp < KP; ++kp) {
            float d = 0.f;
            #pragma unroll
            for (int h = 0; h < 8; ++h) d += snc[kp * 8 + h] * s[h];
            atomicAdd(&dst[kp], d);
        }
        atomicAdd(&dst[KP], n2);
    }
}

// ---------------- K3: score ----------------
__global__ __launch_bounds__(TPB) void score_kernel(
    const float* __restrict__ pdots, const int* __restrict__ ncomp,
    float* __restrict__ out)
{
    __shared__ float red[5][TPB];
    const int b = blockIdx.x, t = threadIdx.x;
    const int n = ncomp[b];
    float ak[5] = {0.f, 0.f, 0.f, 0.f, 0.f};
    for (int j = t; j < n; j += TPB) {
        const float* d = pdots + (size_t)(b * MAXC + j) * 16;
        float4 d0 = *(const float4*)(d + 0);
        float4 d1 = *(const float4*)(d + 4);
        float4 d2 = *(const float4*)(d + 8);
        float4 d3 = *(const float4*)(d + 12);
        float inv = 1.f / fmaxf(sqrtf(d3.w), 1e-12f);
        ak[0] += fmaxf(fmaxf(d0.x, d0.y), d0.z) * inv;
        ak[1] += fmaxf(fmaxf(d0.w, d1.x), d1.y) * inv;
        ak[2] += fmaxf(fmaxf(d1.z, d1.w), d2.x) * inv;
        ak[3] += fmaxf(fmaxf(d2.y, d2.z), d2.w) * inv;
        ak[4] += fmaxf(fmaxf(d3.x, d3.y), d3.z) * inv;
    }
    #pragma unroll
    for (int k = 0; k < 5; ++k) red[k][t] = ak[k];
    __syncthreads();
    for (int s = TPB / 2; s > 0; s >>= 1) {
        if (t < s) {
            #pragma unroll
            for (int k = 0; k < 5; ++k) red[k][t] += red[k][t + s];
        }
        __syncthreads();
    }
    if (t < 5) out[b * 5 + t] = red[t][0] / (float)max(n, 1);
}

extern "C" void kernel_launch(void* const* d_in, const int* in_sizes, int n_in,
                              void* d_out, int out_size, void* d_ws, size_t ws_size,
                              hipStream_t stream)
{
    const float* feat = (const float*)d_in[0];
    const int*   mask = (const int*)d_in[1];
    const float* sfc  = (const float*)d_in[2];
    float* out = (float*)d_out;
    char* ws = (char*)d_ws;

    // ws layout
    int*   cid   = (int*)ws;                                   // 64*4096*4 = 1 MB
    int*   ncomp = (int*)(ws + 1048576);                       // 256 B
    float* sn    = (float*)(ws + 1048576 + 1024);              // 15*256*4 = 15360 B
    float* pdots = (float*)(ws + 1048576 + 1024 + 15360);      // 64*1024*16*4 = 4 MB

    hipMemsetAsync(pdots, 0, (size_t)NB * MAXC * 16 * 4, stream);
    sfc_norm_kernel<<<1, TPB, 0, stream>>>(sfc, sn);
    ccl_compact_kernel<<<NB, TPB, 0, stream>>>(mask, cid, ncomp);
    accum_kernel<<<dim3(32, NB), TPB, 0, stream>>>(feat, sn, cid, ncomp, pdots);
    score_kernel<<<NB, TPB, 0, stream>>>(pdots, ncomp, out);
}

// Round 3
// 495.712 us; speedup vs baseline: 1.9228x; 1.9228x over previous
//
#include <hip/hip_runtime.h>

#define TPB     256
#define CCL_TPB 1024
#define S_PIX   4096   // 64*64
#define NCH     256
#define NB      64
#define MAXC    1024   // max 8-connected comps in 64x64 (king-graph independent set)
#define KP      15     // K*P

// ---------------- K0: normalize SFC prototypes ----------------
__global__ __launch_bounds__(TPB) void sfc_norm_kernel(
    const float* __restrict__ sfc, float* __restrict__ sn)
{
    int t = threadIdx.x;
    int kp = t >> 4, l = t & 15;
    if (kp < KP) {
        const float* v = sfc + kp * NCH;
        float s = 0.f;
        for (int c = l; c < NCH; c += 16) { float x = v[c]; s += x * x; }
        #pragma unroll
        for (int m = 8; m >= 1; m >>= 1) s += __shfl_xor(s, m, 16);
        float inv = 1.f / fmaxf(sqrtf(s), 1e-12f);
        for (int c = l; c < NCH; c += 16) sn[kp * NCH + c] = v[c] * inv;
    }
}

// ---------------- K1: single-pass union-find CCL + compaction ----------------
__device__ __forceinline__ int uf_find(int* lab, int x) {
    int p = lab[x];
    while (p != lab[p]) p = lab[p];
    return p;
}
__device__ __forceinline__ void uf_merge(int* lab, int a, int b) {
    for (;;) {
        a = uf_find(lab, a);
        b = uf_find(lab, b);
        if (a == b) return;
        int mx = a > b ? a : b;
        int mn = a > b ? b : a;
        int old = atomicMin(&lab[mx], mn);
        if (old == mx) return;
        a = old; b = mn;
    }
}

__global__ __launch_bounds__(CCL_TPB) void ccl_uf_kernel(
    const int* __restrict__ mask, int* __restrict__ cid,
    int* __restrict__ ncomp, int* __restrict__ gcomp)
{
    __shared__ int lab[S_PIX];   // 16 KB: parent pointers / final root
    __shared__ int sz[S_PIX];    // 16 KB: per-root size
    __shared__ int rid[S_PIX];   // 16 KB: root -> dense id
    __shared__ int cnt, gpack;
    const int b = blockIdx.x, t = threadIdx.x;
    const int* mb = mask + b * S_PIX;

    for (int i = t; i < S_PIX; i += CCL_TPB) {
        lab[i] = (mb[i] > 0) ? i : -1;
        sz[i] = 0;
    }
    if (t == 0) { cnt = 0; gpack = -1; }
    __syncthreads();

    // union over backward edges (W, N, NW, NE) — each undirected edge once
    for (int i = t; i < S_PIX; i += CCL_TPB) {
        if (lab[i] < 0) continue;
        int x = i & 63;
        if (x > 0 && lab[i - 1] >= 0) uf_merge(lab, i, i - 1);
        if (i >= 64) {
            if (lab[i - 64] >= 0) uf_merge(lab, i, i - 64);
            if (x > 0  && lab[i - 65] >= 0) uf_merge(lab, i, i - 65);
            if (x < 63 && lab[i - 63] >= 0) uf_merge(lab, i, i - 63);
        }
    }
    __syncthreads();

    // full path compression + component sizes
    for (int i = t; i < S_PIX; i += CCL_TPB) {
        if (lab[i] >= 0) {
            int r = uf_find(lab, i);
            lab[i] = r;
            atomicAdd(&sz[r], 1);
        }
    }
    __syncthreads();

    // dense ids for roots; track giant component (max size)
    for (int i = t; i < S_PIX; i += CCL_TPB) {
        if (lab[i] == i) {
            int d = atomicAdd(&cnt, 1);
            rid[i] = d;
            atomicMax(&gpack, (sz[i] << 13) | d);   // sz<=4096 fits above 13 bits of id
        }
    }
    __syncthreads();

    int* co = cid + b * S_PIX;
    for (int i = t; i < S_PIX; i += CCL_TPB) {
        int l = lab[i];
        co[i] = (l >= 0) ? rid[l] : -1;
    }
    if (t == 0) { ncomp[b] = cnt; gcomp[b] = (gpack >= 0) ? (gpack & 8191) : -1; }
}

// ---------------- K2: per-comp channel sums -> partial dots + norm^2 ----------------
__global__ __launch_bounds__(TPB) void accum_kernel(
    const float* __restrict__ feat, const float* __restrict__ sn,
    const int* __restrict__ cid, const int* __restrict__ ncomp,
    const int* __restrict__ gcomp, float* __restrict__ pdots)
{
    __shared__ __align__(16) int scid[S_PIX];   // 16 KB
    __shared__ float acc[8 * MAXC];             // 32 KB, [ch_local][comp]
    __shared__ float snc[KP * 8];
    const int b  = blockIdx.y;
    const int c0 = blockIdx.x * 8;
    const int t  = threadIdx.x;

    {
        const int4* src = reinterpret_cast<const int4*>(cid + b * S_PIX);
        int4* dst = reinterpret_cast<int4*>(scid);
        for (int i = t; i < S_PIX / 4; i += TPB) dst[i] = src[i];
    }
    for (int i = t; i < 8 * MAXC; i += TPB) acc[i] = 0.f;
    if (t < KP * 8) {
        int kp = t >> 3, h = t & 7;
        snc[t] = sn[kp * NCH + c0 + h];
    }
    __syncthreads();

    const int gc = gcomp[b];
    const int wave = t >> 6, lane = t & 63;
    const int chl0 = wave * 2;
    const float* fb  = feat + (size_t)b * NCH * S_PIX;
    const float* fr0 = fb + (size_t)(c0 + chl0) * S_PIX;
    const float* fr1 = fr0 + S_PIX;
    float* a0 = acc + chl0 * MAXC;
    float* a1 = a0 + MAXC;
    float g0 = 0.f, g1 = 0.f;

    auto flush0 = [&](int c, float r) {
        if (c >= 0) { if (c == gc) g0 += r; else atomicAdd(&a0[c], r); }
    };
    auto flush1 = [&](int c, float r) {
        if (c >= 0) { if (c == gc) g1 += r; else atomicAdd(&a1[c], r); }
    };

    for (int base = 0; base < S_PIX; base += 256) {
        const int p = base + lane * 4;
        int4 q = *reinterpret_cast<const int4*>(&scid[p]);
        if ((q.x & q.y & q.z & q.w) == -1) continue;   // all background
        float4 v0 = *reinterpret_cast<const float4*>(&fr0[p]);
        float4 v1 = *reinterpret_cast<const float4*>(&fr1[p]);
        {
            int cur = q.x; float rs = v0.x;
            if (q.y == cur) rs += v0.y; else { flush0(cur, rs); cur = q.y; rs = v0.y; }
            if (q.z == cur) rs += v0.z; else { flush0(cur, rs); cur = q.z; rs = v0.z; }
            if (q.w == cur) rs += v0.w; else { flush0(cur, rs); cur = q.w; rs = v0.w; }
            flush0(cur, rs);
        }
        {
            int cur = q.x; float rs = v1.x;
            if (q.y == cur) rs += v1.y; else { flush1(cur, rs); cur = q.y; rs = v1.y; }
            if (q.z == cur) rs += v1.z; else { flush1(cur, rs); cur = q.z; rs = v1.z; }
            if (q.w == cur) rs += v1.w; else { flush1(cur, rs); cur = q.w; rs = v1.w; }
            flush1(cur, rs);
        }
    }
    #pragma unroll
    for (int m = 32; m >= 1; m >>= 1) {
        g0 += __shfl_xor(g0, m);
        g1 += __shfl_xor(g1, m);
    }
    if (lane == 0 && gc >= 0) { a0[gc] = g0; a1[gc] = g1; }   // sole writer of gc slot
    __syncthreads();

    const int n = ncomp[b];
    for (int j = t; j < n; j += TPB) {
        float s[8]; float n2 = 0.f;
        #pragma unroll
        for (int h = 0; h < 8; ++h) { float x = acc[h * MAXC + j]; s[h] = x; n2 += x * x; }
        float* dst = pdots + (size_t)(b * MAXC + j) * 16;
        #pragma unroll
        for (int kp = 0; kp < KP; ++kp) {
            float d = 0.f;
            #pragma unroll
            for (int h = 0; h < 8; ++h) d += snc[kp * 8 + h] * s[h];
            atomicAdd(&dst[kp], d);
        }
        atomicAdd(&dst[KP], n2);
    }
}

// ---------------- K3: score ----------------
__global__ __launch_bounds__(TPB) void score_kernel(
    const float* __restrict__ pdots, const int* __restrict__ ncomp,
    float* __restrict__ out)
{
    __shared__ float red[5][TPB];
    const int b = blockIdx.x, t = threadIdx.x;
    const int n = ncomp[b];
    float ak[5] = {0.f, 0.f, 0.f, 0.f, 0.f};
    for (int j = t; j < n; j += TPB) {
        const float* d = pdots + (size_t)(b * MAXC + j) * 16;
        float4 d0 = *(const float4*)(d + 0);
        float4 d1 = *(const float4*)(d + 4);
        float4 d2 = *(const float4*)(d + 8);
        float4 d3 = *(const float4*)(d + 12);
        float inv = 1.f / fmaxf(sqrtf(d3.w), 1e-12f);
        ak[0] += fmaxf(fmaxf(d0.x, d0.y), d0.z) * inv;
        ak[1] += fmaxf(fmaxf(d0.w, d1.x), d1.y) * inv;
        ak[2] += fmaxf(fmaxf(d1.z, d1.w), d2.x) * inv;
        ak[3] += fmaxf(fmaxf(d2.y, d2.z), d2.w) * inv;
        ak[4] += fmaxf(fmaxf(d3.x, d3.y), d3.z) * inv;
    }
    #pragma unroll
    for (int k = 0; k < 5; ++k) red[k][t] = ak[k];
    __syncthreads();
    for (int s = TPB / 2; s > 0; s >>= 1) {
        if (t < s) {
            #pragma unroll
            for (int k = 0; k < 5; ++k) red[k][t] += red[k][t + s];
        }
        __syncthreads();
    }
    if (t < 5) out[b * 5 + t] = red[t][0] / (float)max(n, 1);
}

extern "C" void kernel_launch(void* const* d_in, const int* in_sizes, int n_in,
                              void* d_out, int out_size, void* d_ws, size_t ws_size,
                              hipStream_t stream)
{
    const float* feat = (const float*)d_in[0];
    const int*   mask = (const int*)d_in[1];
    const float* sfc  = (const float*)d_in[2];
    float* out = (float*)d_out;
    char* ws = (char*)d_ws;

    int*   cid   = (int*)ws;                                   // 1 MB
    int*   ncomp = (int*)(ws + 1048576);                       // 256 B
    int*   gcomp = (int*)(ws + 1048576 + 1024);                // 256 B
    float* sn    = (float*)(ws + 1048576 + 2048);              // 15 KB
    float* pdots = (float*)(ws + 1048576 + 2048 + 15360);      // 4 MB

    hipMemsetAsync(pdots, 0, (size_t)NB * MAXC * 16 * 4, stream);
    sfc_norm_kernel<<<1, TPB, 0, stream>>>(sfc, sn);
    ccl_uf_kernel<<<NB, CCL_TPB, 0, stream>>>(mask, cid, ncomp, gcomp);
    accum_kernel<<<dim3(32, NB), TPB, 0, stream>>>(feat, sn, cid, ncomp, gcomp, pdots);
    score_kernel<<<NB, TPB, 0, stream>>>(pdots, ncomp, out);
}